// Round 1
// baseline (261.328 us; speedup 1.0000x reference)
//
#include <hip/hip_runtime.h>

#define LSIDE 128
#define NB 16

__global__ __launch_bounds__(256) void ProjectorMultiRes_59236188947236_kernel(
    const float* __restrict__ rotmat,
    const float* __restrict__ vol,
    const float* __restrict__ coords,
    float* __restrict__ out)
{
    __shared__ float lin[LSIDE];
    const int tid = threadIdx.x;
    if (tid < LSIDE) lin[tid] = coords[3 * tid + 2];  // coords[k][2] = lin[k]
    __syncthreads();

    // blockIdx.x = b * 64 + blk ; each block does 2 rows (i) x 128 cols (j)
    const int blocks_per_b = (LSIDE * LSIDE) / 256;  // 64
    const int b   = blockIdx.x / blocks_per_b;
    const int blk = blockIdx.x % blocks_per_b;
    const int i = blk * 2 + (tid >> 7);
    const int j = tid & 127;

    const float* R = rotmat + b * 9;  // [3][3] row-major
    const float r00 = R[0], r01 = R[1], r02 = R[2];
    const float r10 = R[3], r11 = R[4], r12 = R[5];
    const float r20 = R[6], r21 = R[7], r22 = R[8];

    const float lj = lin[j];
    const float li = lin[i];
    // base point of the line (in [-1,1] space), direction = row 2 of R
    const float bx = lj * r00 + li * r10;
    const float by = lj * r01 + li * r11;
    const float bz = lj * r02 + li * r12;

    const float s = 0.5f * (float)(LSIDE - 1);  // 63.5, align_corners=True

    float acc = 0.0f;

    for (int k = 0; k < LSIDE; ++k) {
        const float lk = lin[k];
        // pts = (x,y,z); x indexes W (last dim), y indexes H, z indexes D
        const float gx = (bx + lk * r20 + 1.0f) * s;
        const float gy = (by + lk * r21 + 1.0f) * s;
        const float gz = (bz + lk * r22 + 1.0f) * s;

        const float fx = floorf(gx), fy = floorf(gy), fz = floorf(gz);
        int x0 = (int)fx, y0 = (int)fy, z0 = (int)fz;
        const float wx1 = gx - fx, wy1 = gy - fy, wz1 = gz - fz;
        const float wx0 = 1.0f - wx1, wy0 = 1.0f - wy1, wz0 = 1.0f - wz1;

        // whole-sample reject: all 8 corners out of bounds on some axis
        if (x0 < -1 || x0 >= LSIDE || y0 < -1 || y0 >= LSIDE ||
            z0 < -1 || z0 >= LSIDE)
            continue;

        if (x0 >= 0 && x0 < LSIDE - 1 &&
            y0 >= 0 && y0 < LSIDE - 1 &&
            z0 >= 0 && z0 < LSIDE - 1) {
            // interior fast path: 8 unguarded loads
            const float* p = vol + ((z0 * LSIDE) + y0) * LSIDE + x0;
            const float v000 = p[0];
            const float v001 = p[1];
            const float v010 = p[LSIDE];
            const float v011 = p[LSIDE + 1];
            const float v100 = p[LSIDE * LSIDE];
            const float v101 = p[LSIDE * LSIDE + 1];
            const float v110 = p[LSIDE * LSIDE + LSIDE];
            const float v111 = p[LSIDE * LSIDE + LSIDE + 1];
            const float vx00 = v000 * wx0 + v001 * wx1;
            const float vx01 = v010 * wx0 + v011 * wx1;
            const float vx10 = v100 * wx0 + v101 * wx1;
            const float vx11 = v110 * wx0 + v111 * wx1;
            const float vxy0 = vx00 * wy0 + vx01 * wy1;
            const float vxy1 = vx10 * wy0 + vx11 * wy1;
            acc += vxy0 * wz0 + vxy1 * wz1;
        } else {
            // boundary: branchless clamped loads * validity mask (zeros padding)
            const int x1 = x0 + 1, y1 = y0 + 1, z1 = z0 + 1;
            const float mx0 = ((unsigned)x0 < LSIDE) ? 1.0f : 0.0f;
            const float mx1 = ((unsigned)x1 < LSIDE) ? 1.0f : 0.0f;
            const float my0 = ((unsigned)y0 < LSIDE) ? 1.0f : 0.0f;
            const float my1 = ((unsigned)y1 < LSIDE) ? 1.0f : 0.0f;
            const float mz0 = ((unsigned)z0 < LSIDE) ? 1.0f : 0.0f;
            const float mz1 = ((unsigned)z1 < LSIDE) ? 1.0f : 0.0f;
            const int cx0 = min(max(x0, 0), LSIDE - 1);
            const int cx1 = min(max(x1, 0), LSIDE - 1);
            const int cy0 = min(max(y0, 0), LSIDE - 1);
            const int cy1 = min(max(y1, 0), LSIDE - 1);
            const int cz0 = min(max(z0, 0), LSIDE - 1);
            const int cz1 = min(max(z1, 0), LSIDE - 1);
            const float v000 = vol[(cz0 * LSIDE + cy0) * LSIDE + cx0] * mz0 * my0 * mx0;
            const float v001 = vol[(cz0 * LSIDE + cy0) * LSIDE + cx1] * mz0 * my0 * mx1;
            const float v010 = vol[(cz0 * LSIDE + cy1) * LSIDE + cx0] * mz0 * my1 * mx0;
            const float v011 = vol[(cz0 * LSIDE + cy1) * LSIDE + cx1] * mz0 * my1 * mx1;
            const float v100 = vol[(cz1 * LSIDE + cy0) * LSIDE + cx0] * mz1 * my0 * mx0;
            const float v101 = vol[(cz1 * LSIDE + cy0) * LSIDE + cx1] * mz1 * my0 * mx1;
            const float v110 = vol[(cz1 * LSIDE + cy1) * LSIDE + cx0] * mz1 * my1 * mx0;
            const float v111 = vol[(cz1 * LSIDE + cy1) * LSIDE + cx1] * mz1 * my1 * mx1;
            const float vx00 = v000 * wx0 + v001 * wx1;
            const float vx01 = v010 * wx0 + v011 * wx1;
            const float vx10 = v100 * wx0 + v101 * wx1;
            const float vx11 = v110 * wx0 + v111 * wx1;
            const float vxy0 = vx00 * wy0 + vx01 * wy1;
            const float vxy1 = vx10 * wy0 + vx11 * wy1;
            acc += vxy0 * wz0 + vxy1 * wz1;
        }
    }

    out[(b * LSIDE + i) * LSIDE + j] = acc;
}

extern "C" void kernel_launch(void* const* d_in, const int* in_sizes, int n_in,
                              void* d_out, int out_size, void* d_ws, size_t ws_size,
                              hipStream_t stream) {
    const float* rotmat = (const float*)d_in[0];
    const float* vol    = (const float*)d_in[1];
    const float* coords = (const float*)d_in[2];
    float* out = (float*)d_out;

    const int grid = NB * (LSIDE * LSIDE) / 256;  // 1024 blocks
    ProjectorMultiRes_59236188947236_kernel<<<grid, 256, 0, stream>>>(
        rotmat, vol, coords, out);
}